// Round 13
// baseline (361.137 us; speedup 1.0000x reference)
//
#include <hip/hip_runtime.h>
#include <hip/hip_fp16.h>
#include <math.h>

#define NNODES 50000
#define NEDGES 800000
#define HD     128      // H*D
#define NHEADS 4
#define DH     32

#define TILE_R 64       // gemm rows per block
#define AKP    40       // padded k-stride (halves) for fp16 LDS tiles

#define PTILE  128      // proj rows per block; split-K=2 partial buffers + reduce
                        // (round-6 lesson: NEVER split-K via global atomicAdd)

// Bucketed CSR build (round-9 lesson: naive 4B random scatter = 17x write amp;
// all fine-grained scatter must happen in LDS).
#define NBUCK  196
#define BCAP   6144
#define P1_T   512
#define P1_EPB 4096
#define P2_T   512

struct alignas(16) Half8 { __half2 a, b, c, d; };
typedef _Float16 f16x8 __attribute__((ext_vector_type(8)));
typedef float    f32x4 __attribute__((ext_vector_type(4)));

static __device__ __forceinline__ float lrelu(float x){ return x > 0.f ? x : 0.2f*x; }
static __device__ __forceinline__ float elu(float x){ return x > 0.f ? x : __expf(x) - 1.f; }

// ---------------- CSR build, bucketed ----------------

__global__ void init_btail_kernel(int* btail){
  int b = blockIdx.x*blockDim.x + threadIdx.x;
  if (b < NBUCK) btail[b] = b*BCAP;
}

__global__ __launch_bounds__(P1_T) void p1_bucket_kernel(
    const int* __restrict__ src, const int* __restrict__ dst,
    int* __restrict__ btail, unsigned int* __restrict__ bstage, int e)
{
  __shared__ int cnt[NBUCK];
  __shared__ int gstart[NBUCK];
  int t = threadIdx.x;
  int base = blockIdx.x * P1_EPB;
  for (int i = t; i < NBUCK; i += P1_T) cnt[i] = 0;
  __syncthreads();
  int s_[8], b_[8], dl_[8];
  #pragma unroll
  for (int j = 0; j < 8; j++){
    int i = base + j*P1_T + t;
    if (i < e){
      int d = dst[i];
      s_[j]  = src[i];
      b_[j]  = d >> 8;
      dl_[j] = d & 255;
      atomicAdd(&cnt[b_[j]], 1);
    } else b_[j] = -1;
  }
  __syncthreads();
  for (int i = t; i < NBUCK; i += P1_T){
    gstart[i] = cnt[i] ? atomicAdd(&btail[i], cnt[i]) : 0;
    cnt[i] = 0;
  }
  __syncthreads();
  #pragma unroll
  for (int j = 0; j < 8; j++){
    if (b_[j] >= 0){
      int p = atomicAdd(&cnt[b_[j]], 1);
      bstage[(size_t)gstart[b_[j]] + p] = ((unsigned)dl_[j] << 16) | (unsigned)s_[j];
    }
  }
}

__global__ void bucket_scan_kernel(const int* __restrict__ btail, int* __restrict__ ebase,
                                   int* __restrict__ rowptr){
  if (blockIdx.x == 0 && threadIdx.x == 0){
    int run = 0;
    for (int b = 0; b < NBUCK; b++){
      ebase[b] = run;
      run += btail[b] - b*BCAP;
    }
    rowptr[NNODES] = run;
  }
}

__global__ __launch_bounds__(P2_T) void p2_csr_kernel(
    const unsigned int* __restrict__ bstage, const int* __restrict__ btail,
    const int* __restrict__ ebase, int* __restrict__ rowptr, int* __restrict__ srcs)
{
  __shared__ unsigned int ebuf[BCAP];
  __shared__ unsigned short sorted[BCAP];
  __shared__ int cnt[256], ofs[256], run[256];
  int b = blockIdx.x, t = threadIdx.x;
  int nE = btail[b] - b*BCAP;
  int gb = ebase[b];
  const unsigned int* bp = bstage + (size_t)b*BCAP;

  for (int i = t; i < 256; i += P2_T) cnt[i] = 0;
  __syncthreads();
  for (int i = t; i < nE; i += P2_T){
    unsigned int v = bp[i];
    ebuf[i] = v;
    atomicAdd(&cnt[v >> 16], 1);
  }
  __syncthreads();
  if (t < 256) ofs[t] = cnt[t];
  __syncthreads();
  for (int off = 1; off < 256; off <<= 1){
    int v = 0;
    if (t < 256 && t >= off) v = ofs[t - off];
    __syncthreads();
    if (t < 256) ofs[t] += v;
    __syncthreads();
  }
  if (t < 256){
    int ex = ofs[t] - cnt[t];
    run[t] = ex;
    int node = b*256 + t;
    if (node < NNODES) rowptr[node] = gb + ex;
  }
  __syncthreads();
  for (int i = t; i < nE; i += P2_T){
    unsigned int v = ebuf[i];
    int p = atomicAdd(&run[v >> 16], 1);
    sorted[p] = (unsigned short)(v & 0xFFFFu);
  }
  __syncthreads();
  for (int i = t; i < nE; i += P2_T)
    srcs[gb + i] = (int)sorted[i];
}

// ---------------- W prep: transpose+convert W[l][k][n] -> Wt[l][n][k] fp16 ----------------
__global__ void wprep_kernel(const float* __restrict__ W0, const float* __restrict__ W1,
                             const float* __restrict__ W2, _Float16* __restrict__ wt){
  int id = blockIdx.x*blockDim.x + threadIdx.x;     // 3*16384
  if (id >= 3*16384) return;
  int l = id >> 14, rem = id & 16383;
  int n = rem >> 7, k = rem & 127;
  const float* W = (l==0) ? W0 : (l==1) ? W1 : W2;
  wt[(size_t)l*16384 + n*128 + k] = (_Float16)W[k*128 + n];
}

// ---------------- GEMM (h @ W) via MFMA fp16 + el/er epilogue; feat fp16 ----------------
__global__ __launch_bounds__(256) void gemm_feat_kernel(
    const float* __restrict__ h, int hstride,
    const _Float16* __restrict__ Wt,   // [128 n][128 k] fp16 (pre-transposed)
    const float* __restrict__ al, const float* __restrict__ ar,
    __half* __restrict__ feat, float* __restrict__ elv, float* __restrict__ erv)
{
  __shared__ __align__(16) _Float16 Ah[TILE_R*AKP];   // 5120 B
  __shared__ __align__(16) _Float16 Wh[HD*AKP];       // 10240 B
  int t = threadIdx.x;
  int w = t >> 6, lane = t & 63;
  int c = lane & 15, quad = lane >> 4;
  int rbase = blockIdx.x * TILE_R;

  f32x4 acc[8];
  #pragma unroll
  for (int ct = 0; ct < 8; ct++) acc[ct] = (f32x4){0.f, 0.f, 0.f, 0.f};

  int arow = t >> 2;
  int akq  = t & 3;
  int an   = rbase + arow;
  const float* ap = h + (size_t)an*hstride + akq*8;
  int wn = t >> 1;
  int wk = (t & 1) * 16;
  const _Float16* wp = Wt + wn*HD + wk;

  for (int kb = 0; kb < HD; kb += 32){
    float4 v0 = make_float4(0.f,0.f,0.f,0.f), v1 = v0;
    if (an < NNODES){
      v0 = *(const float4*)(ap + kb);
      v1 = *(const float4*)(ap + kb + 4);
    }
    f16x8 av;
    av[0]=(_Float16)v0.x; av[1]=(_Float16)v0.y; av[2]=(_Float16)v0.z; av[3]=(_Float16)v0.w;
    av[4]=(_Float16)v1.x; av[5]=(_Float16)v1.y; av[6]=(_Float16)v1.z; av[7]=(_Float16)v1.w;
    *(f16x8*)&Ah[arow*AKP + akq*8] = av;
    *(uint4*)&Wh[wn*AKP + wk]     = *(const uint4*)(wp + kb);
    *(uint4*)&Wh[wn*AKP + wk + 8] = *(const uint4*)(wp + kb + 8);
    __syncthreads();

    f16x8 afrag = *(const f16x8*)&Ah[(w*16 + c)*AKP + quad*8];
    #pragma unroll
    for (int ct = 0; ct < 8; ct++){
      f16x8 bfrag = *(const f16x8*)&Wh[(ct*16 + c)*AKP + quad*8];
      acc[ct] = __builtin_amdgcn_mfma_f32_16x16x32_f16(afrag, bfrag, acc[ct], 0, 0, 0);
    }
    __syncthreads();
  }

  float alv[8], arv[8];
  #pragma unroll
  for (int ct = 0; ct < 8; ct++){
    int idx = (ct >> 1)*DH + (ct & 1)*16 + c;
    alv[ct] = al[idx];
    arv[ct] = ar[idx];
  }
  #pragma unroll
  for (int r = 0; r < 4; r++){
    int n = rbase + w*16 + quad*4 + r;
    float pl[4], pr[4];
    #pragma unroll
    for (int hh = 0; hh < 4; hh++){
      pl[hh] = acc[2*hh][r]*alv[2*hh] + acc[2*hh+1][r]*alv[2*hh+1];
      pr[hh] = acc[2*hh][r]*arv[2*hh] + acc[2*hh+1][r]*arv[2*hh+1];
    }
    #pragma unroll
    for (int hh = 0; hh < 4; hh++){
      pl[hh] += __shfl_xor(pl[hh], 1); pl[hh] += __shfl_xor(pl[hh], 2);
      pl[hh] += __shfl_xor(pl[hh], 4); pl[hh] += __shfl_xor(pl[hh], 8);
      pr[hh] += __shfl_xor(pr[hh], 1); pr[hh] += __shfl_xor(pr[hh], 2);
      pr[hh] += __shfl_xor(pr[hh], 4); pr[hh] += __shfl_xor(pr[hh], 8);
    }
    if (n < NNODES){
      if (c < 4){ elv[n*NHEADS + c] = pl[c]; erv[n*NHEADS + c] = pr[c]; }
      #pragma unroll
      for (int ct = 0; ct < 8; ct++)
        feat[(size_t)n*HD + ct*16 + c] = __float2half_rn(acc[ct][r]);
    }
  }
}

// -------- fused edge-softmax + aggregation, 32-edge chunked loads (wave per dst) -----
// Round-12 Little's-law analysis: 8-edges-in-flight gave 256 B outstanding/wave ->
// 5.1 TB/s L2-side capacity == measured 5.2 TB/s (latency-bound). This version
// batches a 32-edge chunk: 4 independent srcs loads, then (once indices land)
// 4 elv + 8 feat loads ALL concurrent -> ~4x outstanding bytes; chain depth 2.
// Invalid tail edges clamp to row 0 with a=0 (hot line, harmless).
// No max subtraction (round-9): exp(e)/sum == exp(e-m)/sum(e-m); e <= ~15 << 88.
__global__ __launch_bounds__(256) void smax_agg_kernel(
    const int* __restrict__ rowptr, const int* __restrict__ srcs,
    const float* __restrict__ elv, const float* __restrict__ erv,
    const __half* __restrict__ feat, float* __restrict__ emb_out, int n)
{
  int wid  = (int)((blockIdx.x*(size_t)blockDim.x + threadIdx.x) >> 6);
  int lane = threadIdx.x & 63;
  if (wid >= n) return;
  int s0 = rowptr[wid], s1 = rowptr[wid+1];
  int g   = lane >> 3;                // edge group 0..7
  int fl8 = lane & 7;                 // feature chunk: features fl8*16..+15
  int fo  = fl8 * 16;

  if (s0 == s1){
    if (g == 0){
      float4 z = make_float4(0.f,0.f,0.f,0.f);
      float* op = emb_out + (size_t)wid*384 + fo;
      *(float4*)(op)      = z;
      *(float4*)(op + 4)  = z;
      *(float4*)(op + 8)  = z;
      *(float4*)(op + 12) = z;
    }
    return;
  }

  float4 er4 = *(const float4*)(erv + (size_t)wid*4);
  int head = fl8 >> 1;
  float erh = (head==0)?er4.x:(head==1)?er4.y:(head==2)?er4.z:er4.w;

  float acc[16];
  #pragma unroll
  for (int j = 0; j < 16; j++) acc[j] = 0.f;
  float ssum = 0.f;

  for (int i = s0; i < s1; i += 32){
    // level 1: 4 independent index loads
    int s[4]; bool v[4];
    #pragma unroll
    for (int j = 0; j < 4; j++){
      int e = i + g + 8*j;
      v[j] = (e < s1);
      s[j] = v[j] ? srcs[e] : 0;
    }
    // level 2: 4 elv + 8 feat loads, all independent once s[] lands
    float a[4];
    Half8 f0[4], f1[4];
    #pragma unroll
    for (int j = 0; j < 4; j++){
      a[j] = v[j] ? __expf(lrelu(elv[(size_t)s[j]*4 + head] + erh)) : 0.f;
      const __half* fr = feat + (size_t)s[j]*HD + fo;
      f0[j] = *(const Half8*)(fr);
      f1[j] = *(const Half8*)(fr + 8);
    }
    // compute
    #pragma unroll
    for (int j = 0; j < 4; j++){
      ssum += a[j];
      float2 p0 = __half22float2(f0[j].a), p1 = __half22float2(f0[j].b);
      float2 p2 = __half22float2(f0[j].c), p3 = __half22float2(f0[j].d);
      float2 p4 = __half22float2(f1[j].a), p5 = __half22float2(f1[j].b);
      float2 p6 = __half22float2(f1[j].c), p7 = __half22float2(f1[j].d);
      float aj = a[j];
      acc[0]  += aj*p0.x; acc[1]  += aj*p0.y; acc[2]  += aj*p1.x; acc[3]  += aj*p1.y;
      acc[4]  += aj*p2.x; acc[5]  += aj*p2.y; acc[6]  += aj*p3.x; acc[7]  += aj*p3.y;
      acc[8]  += aj*p4.x; acc[9]  += aj*p4.y; acc[10] += aj*p5.x; acc[11] += aj*p5.y;
      acc[12] += aj*p6.x; acc[13] += aj*p6.y; acc[14] += aj*p7.x; acc[15] += aj*p7.y;
    }
  }

  #pragma unroll
  for (int j = 0; j < 16; j++){
    acc[j] += __shfl_xor(acc[j], 8);
    acc[j] += __shfl_xor(acc[j], 16);
    acc[j] += __shfl_xor(acc[j], 32);
  }
  ssum += __shfl_xor(ssum, 8);
  ssum += __shfl_xor(ssum, 16);
  ssum += __shfl_xor(ssum, 32);

  if (g == 0){
    float inv = 1.f / ssum;
    float* op = emb_out + (size_t)wid*384 + fo;
    float4 o;
    o.x = elu(acc[0]*inv);  o.y = elu(acc[1]*inv);
    o.z = elu(acc[2]*inv);  o.w = elu(acc[3]*inv);
    *(float4*)(op) = o;
    o.x = elu(acc[4]*inv);  o.y = elu(acc[5]*inv);
    o.z = elu(acc[6]*inv);  o.w = elu(acc[7]*inv);
    *(float4*)(op + 4) = o;
    o.x = elu(acc[8]*inv);  o.y = elu(acc[9]*inv);
    o.z = elu(acc[10]*inv); o.w = elu(acc[11]*inv);
    *(float4*)(op + 8) = o;
    o.x = elu(acc[12]*inv); o.y = elu(acc[13]*inv);
    o.z = elu(acc[14]*inv); o.w = elu(acc[15]*inv);
    *(float4*)(op + 12) = o;
  }
}

// ---------------- final projection: emb[N,384] @ Wproj[384,32], split-K partials --------
__global__ __launch_bounds__(256) void proj_kernel(
    const float* __restrict__ emb, const float* __restrict__ Wp, float* __restrict__ part)
{
  __shared__ float As[PTILE*36];
  __shared__ float Wl[32*32];
  int t = threadIdx.x;
  int tx = t & 3, ty = t >> 2;
  int rbase = blockIdx.x * PTILE;
  int kstart = blockIdx.y * 192;
  float* pout = part + (size_t)blockIdx.y * NNODES * 32;

  float acc[2][8];
  #pragma unroll
  for (int r = 0; r < 2; r++)
    #pragma unroll
    for (int j = 0; j < 8; j++) acc[r][j] = 0.f;

  for (int kb = kstart; kb < kstart + 192; kb += 32){
    #pragma unroll
    for (int i = 0; i < 4; i++){
      int idx = i*256 + t;
      int row = idx >> 3;
      int kq  = (idx & 7) * 4;
      int gr  = rbase + row;
      float4 v = make_float4(0.f,0.f,0.f,0.f);
      if (gr < NNODES) v = *(const float4*)(emb + (size_t)gr*384 + kb + kq);
      *(float4*)&As[row*36 + kq] = v;
    }
    *(float4*)&Wl[t*4] = *(const float4*)(Wp + (size_t)kb*32 + t*4);
    __syncthreads();

    #pragma unroll 8
    for (int k = 0; k < 32; k++){
      float4 b0 = *(const float4*)&Wl[k*32 + tx*8];
      float4 b1 = *(const float4*)&Wl[k*32 + tx*8 + 4];
      #pragma unroll
      for (int r = 0; r < 2; r++){
        float a = As[(ty + 64*r)*36 + k];
        acc[r][0] += a*b0.x; acc[r][1] += a*b0.y;
        acc[r][2] += a*b0.z; acc[r][3] += a*b0.w;
        acc[r][4] += a*b1.x; acc[r][5] += a*b1.y;
        acc[r][6] += a*b1.z; acc[r][7] += a*b1.w;
      }
    }
    __syncthreads();
  }

  #pragma unroll
  for (int r = 0; r < 2; r++){
    int n = rbase + ty + 64*r;
    if (n < NNODES){
      *(float4*)(pout + (size_t)n*32 + tx*8)     = make_float4(acc[r][0], acc[r][1], acc[r][2], acc[r][3]);
      *(float4*)(pout + (size_t)n*32 + tx*8 + 4) = make_float4(acc[r][4], acc[r][5], acc[r][6], acc[r][7]);
    }
  }
}

__global__ void proj_reduce_kernel(const float4* __restrict__ part, float4* __restrict__ out, int n4){
  int i = blockIdx.x*blockDim.x + threadIdx.x;
  if (i >= n4) return;
  float4 a = part[i];
  float4 b = part[n4 + i];
  out[i] = make_float4(a.x + b.x, a.y + b.y, a.z + b.z, a.w + b.w);
}

// ---------------- launch ----------------
extern "C" void kernel_launch(void* const* d_in, const int* in_sizes, int n_in,
                              void* d_out, int out_size, void* d_ws, size_t ws_size,
                              hipStream_t stream) {
  const float* x    = (const float*)d_in[0];
  const int*   src  = (const int*)d_in[1];
  const int*   dst  = (const int*)d_in[2];
  const float* Ws_[3]  = { (const float*)d_in[3], (const float*)d_in[6], (const float*)d_in[9]  };
  const float* als[3] = { (const float*)d_in[4], (const float*)d_in[7], (const float*)d_in[10] };
  const float* ars[3] = { (const float*)d_in[5], (const float*)d_in[8], (const float*)d_in[11] };
  const float* Wproj  = (const float*)d_in[12];
  float* out = (float*)d_out;

  char* wptr = (char*)d_ws;
  auto alloc = [&](size_t bytes) -> void* {
    void* p = (void*)wptr; wptr += (bytes + 255) & ~(size_t)255; return p;
  };
  int*      btail      = (int*)     alloc((size_t)NBUCK*4);
  int*      ebase      = (int*)     alloc((size_t)NBUCK*4);
  unsigned* bstage     = (unsigned*)alloc((size_t)NBUCK*BCAP*4);
  int*      rowptr     = (int*)     alloc((size_t)(NNODES+1)*4);
  int*      src_sorted = (int*)     alloc((size_t)NEDGES*4);
  __half*   feat       = (__half*)  alloc((size_t)NNODES*HD*2);
  float*    elv        = (float*)   alloc((size_t)NNODES*NHEADS*4);
  float*    erv        = (float*)   alloc((size_t)NNODES*NHEADS*4);
  float*    emb        = (float*)   alloc((size_t)NNODES*384*4);
  float*    part       = (float*)   alloc((size_t)2*NNODES*32*4);
  _Float16* wt         = (_Float16*)alloc((size_t)3*HD*HD*2);

  // CSR build, bucketed (LDS-local scatter)
  init_btail_kernel<<<1, 256, 0, stream>>>(btail);
  p1_bucket_kernel<<<(NEDGES + P1_EPB - 1)/P1_EPB, P1_T, 0, stream>>>(
      src, dst, btail, bstage, NEDGES);
  bucket_scan_kernel<<<1, 64, 0, stream>>>(btail, ebase, rowptr);
  p2_csr_kernel<<<NBUCK, P2_T, 0, stream>>>(bstage, btail, ebase, rowptr, src_sorted);

  // W transpose+fp16 prep (all 3 layers)
  wprep_kernel<<<(3*HD*HD + 255)/256, 256, 0, stream>>>(Ws_[0], Ws_[1], Ws_[2], wt);

  const float* hin = x;
  int hstride = 128;
  for (int l = 0; l < 3; l++){
    gemm_feat_kernel<<<(NNODES + TILE_R - 1)/TILE_R, 256, 0, stream>>>(
        hin, hstride, wt + (size_t)l*HD*HD, als[l], ars[l], feat, elv, erv);
    smax_agg_kernel<<<(NNODES*64+255)/256, 256, 0, stream>>>(rowptr, src_sorted, elv, erv,
                                                             feat, emb + (size_t)l*128, NNODES);
    hin = emb + (size_t)l*128;
    hstride = 384;
  }

  dim3 pgrid((NNODES + PTILE - 1)/PTILE, 2);
  proj_kernel<<<pgrid, 256, 0, stream>>>(emb, Wproj, part);
  const int OUT4 = NNODES*32/4;
  proj_reduce_kernel<<<(OUT4+255)/256, 256, 0, stream>>>((const float4*)part, (float4*)out, OUT4);
}

// Round 14
// 324.172 us; speedup vs baseline: 1.1140x; 1.1140x over previous
//
#include <hip/hip_runtime.h>
#include <hip/hip_fp16.h>
#include <math.h>

#define NNODES 50000
#define NEDGES 800000
#define HD     128      // H*D
#define NHEADS 4
#define DH     32

#define TILE_R 64       // gemm rows per block
#define AKPF   136      // full-K padded stride (halves): 272 B/row, 16B-aligned,
                        // b128 reads spread 8 dwords/bank uniformly

#define PTILE  128      // proj rows per block; split-K=2 partial buffers + reduce
                        // (round-6 lesson: NEVER split-K via global atomicAdd)

// Bucketed CSR build (round-9 lesson: naive 4B random scatter = 17x write amp;
// all fine-grained scatter must happen in LDS).
#define NBUCK  196
#define BCAP   6144
#define P1_T   512
#define P1_EPB 4096
#define P2_T   512

struct alignas(16) Half8 { __half2 a, b, c, d; };
typedef _Float16 f16x8 __attribute__((ext_vector_type(8)));
typedef float    f32x4 __attribute__((ext_vector_type(4)));

static __device__ __forceinline__ float lrelu(float x){ return x > 0.f ? x : 0.2f*x; }
static __device__ __forceinline__ float elu(float x){ return x > 0.f ? x : __expf(x) - 1.f; }

// ---------------- CSR build, bucketed ----------------

__global__ void init_btail_kernel(int* btail){
  int b = blockIdx.x*blockDim.x + threadIdx.x;
  if (b < NBUCK) btail[b] = b*BCAP;
}

__global__ __launch_bounds__(P1_T) void p1_bucket_kernel(
    const int* __restrict__ src, const int* __restrict__ dst,
    int* __restrict__ btail, unsigned int* __restrict__ bstage, int e)
{
  __shared__ int cnt[NBUCK];
  __shared__ int gstart[NBUCK];
  int t = threadIdx.x;
  int base = blockIdx.x * P1_EPB;
  for (int i = t; i < NBUCK; i += P1_T) cnt[i] = 0;
  __syncthreads();
  int s_[8], b_[8], dl_[8];
  #pragma unroll
  for (int j = 0; j < 8; j++){
    int i = base + j*P1_T + t;
    if (i < e){
      int d = dst[i];
      s_[j]  = src[i];
      b_[j]  = d >> 8;
      dl_[j] = d & 255;
      atomicAdd(&cnt[b_[j]], 1);
    } else b_[j] = -1;
  }
  __syncthreads();
  for (int i = t; i < NBUCK; i += P1_T){
    gstart[i] = cnt[i] ? atomicAdd(&btail[i], cnt[i]) : 0;
    cnt[i] = 0;
  }
  __syncthreads();
  #pragma unroll
  for (int j = 0; j < 8; j++){
    if (b_[j] >= 0){
      int p = atomicAdd(&cnt[b_[j]], 1);
      bstage[(size_t)gstart[b_[j]] + p] = ((unsigned)dl_[j] << 16) | (unsigned)s_[j];
    }
  }
}

__global__ void bucket_scan_kernel(const int* __restrict__ btail, int* __restrict__ ebase,
                                   int* __restrict__ rowptr){
  if (blockIdx.x == 0 && threadIdx.x == 0){
    int run = 0;
    for (int b = 0; b < NBUCK; b++){
      ebase[b] = run;
      run += btail[b] - b*BCAP;
    }
    rowptr[NNODES] = run;
  }
}

__global__ __launch_bounds__(P2_T) void p2_csr_kernel(
    const unsigned int* __restrict__ bstage, const int* __restrict__ btail,
    const int* __restrict__ ebase, int* __restrict__ rowptr, int* __restrict__ srcs)
{
  __shared__ unsigned int ebuf[BCAP];
  __shared__ unsigned short sorted[BCAP];
  __shared__ int cnt[256], ofs[256], run[256];
  int b = blockIdx.x, t = threadIdx.x;
  int nE = btail[b] - b*BCAP;
  int gb = ebase[b];
  const unsigned int* bp = bstage + (size_t)b*BCAP;

  for (int i = t; i < 256; i += P2_T) cnt[i] = 0;
  __syncthreads();
  for (int i = t; i < nE; i += P2_T){
    unsigned int v = bp[i];
    ebuf[i] = v;
    atomicAdd(&cnt[v >> 16], 1);
  }
  __syncthreads();
  if (t < 256) ofs[t] = cnt[t];
  __syncthreads();
  for (int off = 1; off < 256; off <<= 1){
    int v = 0;
    if (t < 256 && t >= off) v = ofs[t - off];
    __syncthreads();
    if (t < 256) ofs[t] += v;
    __syncthreads();
  }
  if (t < 256){
    int ex = ofs[t] - cnt[t];
    run[t] = ex;
    int node = b*256 + t;
    if (node < NNODES) rowptr[node] = gb + ex;
  }
  __syncthreads();
  for (int i = t; i < nE; i += P2_T){
    unsigned int v = ebuf[i];
    int p = atomicAdd(&run[v >> 16], 1);
    sorted[p] = (unsigned short)(v & 0xFFFFu);
  }
  __syncthreads();
  for (int i = t; i < nE; i += P2_T)
    srcs[gb + i] = (int)sorted[i];
}

// ---------------- W prep: transpose+convert W[l][k][n] -> Wt[l][n][k] fp16 ----------------
__global__ void wprep_kernel(const float* __restrict__ W0, const float* __restrict__ W1,
                             const float* __restrict__ W2, _Float16* __restrict__ wt){
  int id = blockIdx.x*blockDim.x + threadIdx.x;     // 3*16384
  if (id >= 3*16384) return;
  int l = id >> 14, rem = id & 16383;
  int n = rem >> 7, k = rem & 127;
  const float* W = (l==0) ? W0 : (l==1) ? W1 : W2;
  wt[(size_t)l*16384 + n*128 + k] = (_Float16)W[k*128 + n];
}

// ---------------- GEMM (h @ W) via MFMA fp16, full-K single-barrier staging ----------------
// Round-13 analysis: per-chunk staging had 8 barriers/block with ~40 cyc of MFMA
// between ~600-cyc staging waits — barrier-drain bound. Here ALL of A (64x128)
// and W (128x128) are staged fp16 into LDS with every global load independent
// (8 A-loads + 8 W-loads per thread in flight), ONE barrier, then 32 MFMAs
// straight from LDS. LDS = 51 KB -> 3 blocks/CU; grid 782 ~ 3.05/CU (matched).
// mfma_f32_16x16x32_f16: A[m=lane&15][k=quad*8+j], B[k=quad*8+j][n=lane&15],
// C: col=lane&15, row=quad*4+reg (verified layouts, learn_hip m89/m120).
__global__ __launch_bounds__(256) void gemm_feat_kernel(
    const float* __restrict__ h, int hstride,
    const _Float16* __restrict__ Wt,   // [128 n][128 k] fp16 (pre-transposed)
    const float* __restrict__ al, const float* __restrict__ ar,
    __half* __restrict__ feat, float* __restrict__ elv, float* __restrict__ erv)
{
  __shared__ __align__(16) _Float16 Ah[TILE_R*AKPF];  // 17408 B
  __shared__ __align__(16) _Float16 Wh[HD*AKPF];      // 34816 B
  int t = threadIdx.x;
  int w = t >> 6, lane = t & 63;
  int c = lane & 15, quad = lane >> 4;
  int rbase = blockIdx.x * TILE_R;

  f32x4 acc[8];
  #pragma unroll
  for (int ct = 0; ct < 8; ct++) acc[ct] = (f32x4){0.f, 0.f, 0.f, 0.f};

  // stage ALL of A: each thread 4 chunks x 8 halves (8 independent float4 loads)
  int arow = t >> 2;
  int akq  = t & 3;
  int an   = rbase + arow;
  const float* ap = h + (size_t)an*hstride + akq*8;
  #pragma unroll
  for (int kb = 0; kb < HD; kb += 32){
    float4 v0 = make_float4(0.f,0.f,0.f,0.f), v1 = v0;
    if (an < NNODES){
      v0 = *(const float4*)(ap + kb);
      v1 = *(const float4*)(ap + kb + 4);
    }
    f16x8 av;
    av[0]=(_Float16)v0.x; av[1]=(_Float16)v0.y; av[2]=(_Float16)v0.z; av[3]=(_Float16)v0.w;
    av[4]=(_Float16)v1.x; av[5]=(_Float16)v1.y; av[6]=(_Float16)v1.z; av[7]=(_Float16)v1.w;
    *(f16x8*)&Ah[arow*AKPF + kb + akq*8] = av;
  }
  // stage ALL of W: each thread 4 chunks x 16 halves (8 independent uint4 loads)
  int wn = t >> 1;
  int wk = (t & 1) * 16;
  const _Float16* wp = Wt + wn*HD + wk;
  #pragma unroll
  for (int kb = 0; kb < HD; kb += 32){
    *(uint4*)&Wh[wn*AKPF + kb + wk]     = *(const uint4*)(wp + kb);
    *(uint4*)&Wh[wn*AKPF + kb + wk + 8] = *(const uint4*)(wp + kb + 8);
  }
  __syncthreads();

  #pragma unroll
  for (int kb = 0; kb < HD; kb += 32){
    f16x8 afrag = *(const f16x8*)&Ah[(w*16 + c)*AKPF + kb + quad*8];
    #pragma unroll
    for (int ct = 0; ct < 8; ct++){
      f16x8 bfrag = *(const f16x8*)&Wh[(ct*16 + c)*AKPF + kb + quad*8];
      acc[ct] = __builtin_amdgcn_mfma_f32_16x16x32_f16(afrag, bfrag, acc[ct], 0, 0, 0);
    }
  }

  float alv[8], arv[8];
  #pragma unroll
  for (int ct = 0; ct < 8; ct++){
    int idx = (ct >> 1)*DH + (ct & 1)*16 + c;
    alv[ct] = al[idx];
    arv[ct] = ar[idx];
  }
  #pragma unroll
  for (int r = 0; r < 4; r++){
    int n = rbase + w*16 + quad*4 + r;
    float pl[4], pr[4];
    #pragma unroll
    for (int hh = 0; hh < 4; hh++){
      pl[hh] = acc[2*hh][r]*alv[2*hh] + acc[2*hh+1][r]*alv[2*hh+1];
      pr[hh] = acc[2*hh][r]*arv[2*hh] + acc[2*hh+1][r]*arv[2*hh+1];
    }
    #pragma unroll
    for (int hh = 0; hh < 4; hh++){
      pl[hh] += __shfl_xor(pl[hh], 1); pl[hh] += __shfl_xor(pl[hh], 2);
      pl[hh] += __shfl_xor(pl[hh], 4); pl[hh] += __shfl_xor(pl[hh], 8);
      pr[hh] += __shfl_xor(pr[hh], 1); pr[hh] += __shfl_xor(pr[hh], 2);
      pr[hh] += __shfl_xor(pr[hh], 4); pr[hh] += __shfl_xor(pr[hh], 8);
    }
    if (n < NNODES){
      if (c < 4){ elv[n*NHEADS + c] = pl[c]; erv[n*NHEADS + c] = pr[c]; }
      #pragma unroll
      for (int ct = 0; ct < 8; ct++)
        feat[(size_t)n*HD + ct*16 + c] = __float2half_rn(acc[ct][r]);
    }
  }
}

// -------- fused edge-softmax + aggregation, 8 edges in flight (wave per dst node) -----
// ROUND-12 VERSION RESTORED. Round-13 lesson: 32-edge batching raised VGPR
// 28->44, occupancy 63->44% -> REGRESSED 45->59us. In this latency-bound gather
// TLP beats per-wave ILP; 8 edges / VGPR 28 is the sweet spot.
// No max subtraction (round-9): exp(e)/sum == exp(e-m)/sum(e-m); e <= ~15 << 88.
__global__ __launch_bounds__(256) void smax_agg_kernel(
    const int* __restrict__ rowptr, const int* __restrict__ srcs,
    const float* __restrict__ elv, const float* __restrict__ erv,
    const __half* __restrict__ feat, float* __restrict__ emb_out, int n)
{
  int wid  = (int)((blockIdx.x*(size_t)blockDim.x + threadIdx.x) >> 6);
  int lane = threadIdx.x & 63;
  if (wid >= n) return;
  int s0 = rowptr[wid], s1 = rowptr[wid+1];
  int g   = lane >> 3;                // edge group 0..7
  int fl8 = lane & 7;                 // feature chunk: features fl8*16..+15
  int fo  = fl8 * 16;

  if (s0 == s1){
    if (g == 0){
      float4 z = make_float4(0.f,0.f,0.f,0.f);
      float* op = emb_out + (size_t)wid*384 + fo;
      *(float4*)(op)      = z;
      *(float4*)(op + 4)  = z;
      *(float4*)(op + 8)  = z;
      *(float4*)(op + 12) = z;
    }
    return;
  }

  float4 er4 = *(const float4*)(erv + (size_t)wid*4);
  int head = fl8 >> 1;
  float erh = (head==0)?er4.x:(head==1)?er4.y:(head==2)?er4.z:er4.w;

  float acc[16];
  #pragma unroll
  for (int j = 0; j < 16; j++) acc[j] = 0.f;
  float ssum = 0.f;

  for (int i = s0; i < s1; i += 8){
    int e = i + g;
    bool v = (e < s1);
    int s = v ? srcs[e] : 0;
    float a = 0.f;
    if (v) a = __expf(lrelu(elv[(size_t)s*4 + head] + erh));
    ssum += a;
    const __half* fr = feat + (size_t)s*HD + fo;
    Half8 f0 = *(const Half8*)(fr);
    Half8 f1 = *(const Half8*)(fr + 8);
    float2 p0 = __half22float2(f0.a), p1 = __half22float2(f0.b);
    float2 p2 = __half22float2(f0.c), p3 = __half22float2(f0.d);
    float2 p4 = __half22float2(f1.a), p5 = __half22float2(f1.b);
    float2 p6 = __half22float2(f1.c), p7 = __half22float2(f1.d);
    acc[0]  += a*p0.x; acc[1]  += a*p0.y; acc[2]  += a*p1.x; acc[3]  += a*p1.y;
    acc[4]  += a*p2.x; acc[5]  += a*p2.y; acc[6]  += a*p3.x; acc[7]  += a*p3.y;
    acc[8]  += a*p4.x; acc[9]  += a*p4.y; acc[10] += a*p5.x; acc[11] += a*p5.y;
    acc[12] += a*p6.x; acc[13] += a*p6.y; acc[14] += a*p7.x; acc[15] += a*p7.y;
  }

  #pragma unroll
  for (int j = 0; j < 16; j++){
    acc[j] += __shfl_xor(acc[j], 8);
    acc[j] += __shfl_xor(acc[j], 16);
    acc[j] += __shfl_xor(acc[j], 32);
  }
  ssum += __shfl_xor(ssum, 8);
  ssum += __shfl_xor(ssum, 16);
  ssum += __shfl_xor(ssum, 32);

  if (g == 0){
    float inv = 1.f / ssum;
    float* op = emb_out + (size_t)wid*384 + fo;
    float4 o;
    o.x = elu(acc[0]*inv);  o.y = elu(acc[1]*inv);
    o.z = elu(acc[2]*inv);  o.w = elu(acc[3]*inv);
    *(float4*)(op) = o;
    o.x = elu(acc[4]*inv);  o.y = elu(acc[5]*inv);
    o.z = elu(acc[6]*inv);  o.w = elu(acc[7]*inv);
    *(float4*)(op + 4) = o;
    o.x = elu(acc[8]*inv);  o.y = elu(acc[9]*inv);
    o.z = elu(acc[10]*inv); o.w = elu(acc[11]*inv);
    *(float4*)(op + 8) = o;
    o.x = elu(acc[12]*inv); o.y = elu(acc[13]*inv);
    o.z = elu(acc[14]*inv); o.w = elu(acc[15]*inv);
    *(float4*)(op + 12) = o;
  }
}

// ---------------- final projection: emb[N,384] @ Wproj[384,32], split-K partials --------
__global__ __launch_bounds__(256) void proj_kernel(
    const float* __restrict__ emb, const float* __restrict__ Wp, float* __restrict__ part)
{
  __shared__ float As[PTILE*36];
  __shared__ float Wl[32*32];
  int t = threadIdx.x;
  int tx = t & 3, ty = t >> 2;
  int rbase = blockIdx.x * PTILE;
  int kstart = blockIdx.y * 192;
  float* pout = part + (size_t)blockIdx.y * NNODES * 32;

  float acc[2][8];
  #pragma unroll
  for (int r = 0; r < 2; r++)
    #pragma unroll
    for (int j = 0; j < 8; j++) acc[r][j] = 0.f;

  for (int kb = kstart; kb < kstart + 192; kb += 32){
    #pragma unroll
    for (int i = 0; i < 4; i++){
      int idx = i*256 + t;
      int row = idx >> 3;
      int kq  = (idx & 7) * 4;
      int gr  = rbase + row;
      float4 v = make_float4(0.f,0.f,0.f,0.f);
      if (gr < NNODES) v = *(const float4*)(emb + (size_t)gr*384 + kb + kq);
      *(float4*)&As[row*36 + kq] = v;
    }
    *(float4*)&Wl[t*4] = *(const float4*)(Wp + (size_t)kb*32 + t*4);
    __syncthreads();

    #pragma unroll 8
    for (int k = 0; k < 32; k++){
      float4 b0 = *(const float4*)&Wl[k*32 + tx*8];
      float4 b1 = *(const float4*)&Wl[k*32 + tx*8 + 4];
      #pragma unroll
      for (int r = 0; r < 2; r++){
        float a = As[(ty + 64*r)*36 + k];
        acc[r][0] += a*b0.x; acc[r][1] += a*b0.y;
        acc[r][2] += a*b0.z; acc[r][3] += a*b0.w;
        acc[r][4] += a*b1.x; acc[r][5] += a*b1.y;
        acc[r][6] += a*b1.z; acc[r][7] += a*b1.w;
      }
    }
    __syncthreads();
  }

  #pragma unroll
  for (int r = 0; r < 2; r++){
    int n = rbase + ty + 64*r;
    if (n < NNODES){
      *(float4*)(pout + (size_t)n*32 + tx*8)     = make_float4(acc[r][0], acc[r][1], acc[r][2], acc[r][3]);
      *(float4*)(pout + (size_t)n*32 + tx*8 + 4) = make_float4(acc[r][4], acc[r][5], acc[r][6], acc[r][7]);
    }
  }
}

__global__ void proj_reduce_kernel(const float4* __restrict__ part, float4* __restrict__ out, int n4){
  int i = blockIdx.x*blockDim.x + threadIdx.x;
  if (i >= n4) return;
  float4 a = part[i];
  float4 b = part[n4 + i];
  out[i] = make_float4(a.x + b.x, a.y + b.y, a.z + b.z, a.w + b.w);
}

// ---------------- launch ----------------
extern "C" void kernel_launch(void* const* d_in, const int* in_sizes, int n_in,
                              void* d_out, int out_size, void* d_ws, size_t ws_size,
                              hipStream_t stream) {
  const float* x    = (const float*)d_in[0];
  const int*   src  = (const int*)d_in[1];
  const int*   dst  = (const int*)d_in[2];
  const float* Ws_[3]  = { (const float*)d_in[3], (const float*)d_in[6], (const float*)d_in[9]  };
  const float* als[3] = { (const float*)d_in[4], (const float*)d_in[7], (const float*)d_in[10] };
  const float* ars[3] = { (const float*)d_in[5], (const float*)d_in[8], (const float*)d_in[11] };
  const float* Wproj  = (const float*)d_in[12];
  float* out = (float*)d_out;

  char* wptr = (char*)d_ws;
  auto alloc = [&](size_t bytes) -> void* {
    void* p = (void*)wptr; wptr += (bytes + 255) & ~(size_t)255; return p;
  };
  int*      btail      = (int*)     alloc((size_t)NBUCK*4);
  int*      ebase      = (int*)     alloc((size_t)NBUCK*4);
  unsigned* bstage     = (unsigned*)alloc((size_t)NBUCK*BCAP*4);
  int*      rowptr     = (int*)     alloc((size_t)(NNODES+1)*4);
  int*      src_sorted = (int*)     alloc((size_t)NEDGES*4);
  __half*   feat       = (__half*)  alloc((size_t)NNODES*HD*2);
  float*    elv        = (float*)   alloc((size_t)NNODES*NHEADS*4);
  float*    erv        = (float*)   alloc((size_t)NNODES*NHEADS*4);
  float*    emb        = (float*)   alloc((size_t)NNODES*384*4);
  float*    part       = (float*)   alloc((size_t)2*NNODES*32*4);
  _Float16* wt         = (_Float16*)alloc((size_t)3*HD*HD*2);

  // CSR build, bucketed (LDS-local scatter)
  init_btail_kernel<<<1, 256, 0, stream>>>(btail);
  p1_bucket_kernel<<<(NEDGES + P1_EPB - 1)/P1_EPB, P1_T, 0, stream>>>(
      src, dst, btail, bstage, NEDGES);
  bucket_scan_kernel<<<1, 64, 0, stream>>>(btail, ebase, rowptr);
  p2_csr_kernel<<<NBUCK, P2_T, 0, stream>>>(bstage, btail, ebase, rowptr, src_sorted);

  // W transpose+fp16 prep (all 3 layers)
  wprep_kernel<<<(3*HD*HD + 255)/256, 256, 0, stream>>>(Ws_[0], Ws_[1], Ws_[2], wt);

  const float* hin = x;
  int hstride = 128;
  for (int l = 0; l < 3; l++){
    gemm_feat_kernel<<<(NNODES + TILE_R - 1)/TILE_R, 256, 0, stream>>>(
        hin, hstride, wt + (size_t)l*HD*HD, als[l], ars[l], feat, elv, erv);
    smax_agg_kernel<<<(NNODES*64+255)/256, 256, 0, stream>>>(rowptr, src_sorted, elv, erv,
                                                             feat, emb + (size_t)l*128, NNODES);
    hin = emb + (size_t)l*128;
    hstride = 384;
  }

  dim3 pgrid((NNODES + PTILE - 1)/PTILE, 2);
  proj_kernel<<<pgrid, 256, 0, stream>>>(emb, Wproj, part);
  const int OUT4 = NNODES*32/4;
  proj_reduce_kernel<<<(OUT4+255)/256, 256, 0, stream>>>((const float4*)part, (float4*)out, OUT4);
}

// Round 15
// 318.683 us; speedup vs baseline: 1.1332x; 1.0172x over previous
//
#include <hip/hip_runtime.h>
#include <hip/hip_fp16.h>
#include <math.h>

#define NNODES 50000
#define NEDGES 800000
#define HD     128      // H*D
#define NHEADS 4
#define DH     32

#define TILE_R 64       // gemm rows per block
#define AKPF   136      // full-K padded stride (halves)

#define PTILE  128      // proj rows per block; split-K=2 partial buffers + reduce
                        // (round-6 lesson: NEVER split-K via global atomicAdd)

// Bucketed CSR build (round-9 lesson: naive 4B random scatter = 17x write amp;
// all fine-grained scatter must happen in LDS).
#define NBUCK  196
#define BCAP   6144
#define P1_T   512
#define P1_EPB 4096
#define P2_T   512

struct alignas(16) Half8 { __half2 a, b, c, d; };
typedef _Float16 f16x8 __attribute__((ext_vector_type(8)));
typedef float    f32x4 __attribute__((ext_vector_type(4)));
typedef float    f32x8 __attribute__((ext_vector_type(8)));

static __device__ __forceinline__ float lrelu(float x){ return x > 0.f ? x : 0.2f*x; }
static __device__ __forceinline__ float elu(float x){ return x > 0.f ? x : __expf(x) - 1.f; }

// ---------------- CSR build, bucketed ----------------

__global__ void init_btail_kernel(int* btail){
  int b = blockIdx.x*blockDim.x + threadIdx.x;
  if (b < NBUCK) btail[b] = b*BCAP;
}

__global__ __launch_bounds__(P1_T) void p1_bucket_kernel(
    const int* __restrict__ src, const int* __restrict__ dst,
    int* __restrict__ btail, unsigned int* __restrict__ bstage, int e)
{
  __shared__ int cnt[NBUCK];
  __shared__ int gstart[NBUCK];
  int t = threadIdx.x;
  int base = blockIdx.x * P1_EPB;
  for (int i = t; i < NBUCK; i += P1_T) cnt[i] = 0;
  __syncthreads();
  int s_[8], b_[8], dl_[8];
  #pragma unroll
  for (int j = 0; j < 8; j++){
    int i = base + j*P1_T + t;
    if (i < e){
      int d = dst[i];
      s_[j]  = src[i];
      b_[j]  = d >> 8;
      dl_[j] = d & 255;
      atomicAdd(&cnt[b_[j]], 1);
    } else b_[j] = -1;
  }
  __syncthreads();
  for (int i = t; i < NBUCK; i += P1_T){
    gstart[i] = cnt[i] ? atomicAdd(&btail[i], cnt[i]) : 0;
    cnt[i] = 0;
  }
  __syncthreads();
  #pragma unroll
  for (int j = 0; j < 8; j++){
    if (b_[j] >= 0){
      int p = atomicAdd(&cnt[b_[j]], 1);
      bstage[(size_t)gstart[b_[j]] + p] = ((unsigned)dl_[j] << 16) | (unsigned)s_[j];
    }
  }
}

__global__ void bucket_scan_kernel(const int* __restrict__ btail, int* __restrict__ ebase,
                                   int* __restrict__ rowptr){
  if (blockIdx.x == 0 && threadIdx.x == 0){
    int run = 0;
    for (int b = 0; b < NBUCK; b++){
      ebase[b] = run;
      run += btail[b] - b*BCAP;
    }
    rowptr[NNODES] = run;
  }
}

__global__ __launch_bounds__(P2_T) void p2_csr_kernel(
    const unsigned int* __restrict__ bstage, const int* __restrict__ btail,
    const int* __restrict__ ebase, int* __restrict__ rowptr, int* __restrict__ srcs)
{
  __shared__ unsigned int ebuf[BCAP];
  __shared__ unsigned short sorted[BCAP];
  __shared__ int cnt[256], ofs[256], run[256];
  int b = blockIdx.x, t = threadIdx.x;
  int nE = btail[b] - b*BCAP;
  int gb = ebase[b];
  const unsigned int* bp = bstage + (size_t)b*BCAP;

  for (int i = t; i < 256; i += P2_T) cnt[i] = 0;
  __syncthreads();
  for (int i = t; i < nE; i += P2_T){
    unsigned int v = bp[i];
    ebuf[i] = v;
    atomicAdd(&cnt[v >> 16], 1);
  }
  __syncthreads();
  if (t < 256) ofs[t] = cnt[t];
  __syncthreads();
  for (int off = 1; off < 256; off <<= 1){
    int v = 0;
    if (t < 256 && t >= off) v = ofs[t - off];
    __syncthreads();
    if (t < 256) ofs[t] += v;
    __syncthreads();
  }
  if (t < 256){
    int ex = ofs[t] - cnt[t];
    run[t] = ex;
    int node = b*256 + t;
    if (node < NNODES) rowptr[node] = gb + ex;
  }
  __syncthreads();
  for (int i = t; i < nE; i += P2_T){
    unsigned int v = ebuf[i];
    int p = atomicAdd(&run[v >> 16], 1);
    sorted[p] = (unsigned short)(v & 0xFFFFu);
  }
  __syncthreads();
  for (int i = t; i < nE; i += P2_T)
    srcs[gb + i] = (int)sorted[i];
}

// ---------------- W prep: transpose+convert W[l][k][n] -> Wt[l][n][k] fp16 ----------------
__global__ void wprep_kernel(const float* __restrict__ W0, const float* __restrict__ W1,
                             const float* __restrict__ W2, _Float16* __restrict__ wt){
  int id = blockIdx.x*blockDim.x + threadIdx.x;     // 3*16384
  if (id >= 3*16384) return;
  int l = id >> 14, rem = id & 16383;
  int n = rem >> 7, k = rem & 127;
  const float* W = (l==0) ? W0 : (l==1) ? W1 : W2;
  wt[(size_t)l*16384 + n*128 + k] = (_Float16)W[k*128 + n];
}

// ---------------- GEMM (h @ W) via MFMA fp16, full-K single-barrier staging ----------------
__global__ __launch_bounds__(256) void gemm_feat_kernel(
    const float* __restrict__ h, int hstride,
    const _Float16* __restrict__ Wt,   // [128 n][128 k] fp16 (pre-transposed)
    const float* __restrict__ al, const float* __restrict__ ar,
    __half* __restrict__ feat, float* __restrict__ elv, float* __restrict__ erv)
{
  __shared__ __align__(16) _Float16 Ah[TILE_R*AKPF];  // 17408 B
  __shared__ __align__(16) _Float16 Wh[HD*AKPF];      // 34816 B
  int t = threadIdx.x;
  int w = t >> 6, lane = t & 63;
  int c = lane & 15, quad = lane >> 4;
  int rbase = blockIdx.x * TILE_R;

  f32x4 acc[8];
  #pragma unroll
  for (int ct = 0; ct < 8; ct++) acc[ct] = (f32x4){0.f, 0.f, 0.f, 0.f};

  int arow = t >> 2;
  int akq  = t & 3;
  int an   = rbase + arow;
  const float* ap = h + (size_t)an*hstride + akq*8;
  #pragma unroll
  for (int kb = 0; kb < HD; kb += 32){
    float4 v0 = make_float4(0.f,0.f,0.f,0.f), v1 = v0;
    if (an < NNODES){
      v0 = *(const float4*)(ap + kb);
      v1 = *(const float4*)(ap + kb + 4);
    }
    f16x8 av;
    av[0]=(_Float16)v0.x; av[1]=(_Float16)v0.y; av[2]=(_Float16)v0.z; av[3]=(_Float16)v0.w;
    av[4]=(_Float16)v1.x; av[5]=(_Float16)v1.y; av[6]=(_Float16)v1.z; av[7]=(_Float16)v1.w;
    *(f16x8*)&Ah[arow*AKPF + kb + akq*8] = av;
  }
  int wn = t >> 1;
  int wk = (t & 1) * 16;
  const _Float16* wp = Wt + wn*HD + wk;
  #pragma unroll
  for (int kb = 0; kb < HD; kb += 32){
    *(uint4*)&Wh[wn*AKPF + kb + wk]     = *(const uint4*)(wp + kb);
    *(uint4*)&Wh[wn*AKPF + kb + wk + 8] = *(const uint4*)(wp + kb + 8);
  }
  __syncthreads();

  #pragma unroll
  for (int kb = 0; kb < HD; kb += 32){
    f16x8 afrag = *(const f16x8*)&Ah[(w*16 + c)*AKPF + kb + quad*8];
    #pragma unroll
    for (int ct = 0; ct < 8; ct++){
      f16x8 bfrag = *(const f16x8*)&Wh[(ct*16 + c)*AKPF + kb + quad*8];
      acc[ct] = __builtin_amdgcn_mfma_f32_16x16x32_f16(afrag, bfrag, acc[ct], 0, 0, 0);
    }
  }

  float alv[8], arv[8];
  #pragma unroll
  for (int ct = 0; ct < 8; ct++){
    int idx = (ct >> 1)*DH + (ct & 1)*16 + c;
    alv[ct] = al[idx];
    arv[ct] = ar[idx];
  }
  #pragma unroll
  for (int r = 0; r < 4; r++){
    int n = rbase + w*16 + quad*4 + r;
    float pl[4], pr[4];
    #pragma unroll
    for (int hh = 0; hh < 4; hh++){
      pl[hh] = acc[2*hh][r]*alv[2*hh] + acc[2*hh+1][r]*alv[2*hh+1];
      pr[hh] = acc[2*hh][r]*arv[2*hh] + acc[2*hh+1][r]*arv[2*hh+1];
    }
    #pragma unroll
    for (int hh = 0; hh < 4; hh++){
      pl[hh] += __shfl_xor(pl[hh], 1); pl[hh] += __shfl_xor(pl[hh], 2);
      pl[hh] += __shfl_xor(pl[hh], 4); pl[hh] += __shfl_xor(pl[hh], 8);
      pr[hh] += __shfl_xor(pr[hh], 1); pr[hh] += __shfl_xor(pr[hh], 2);
      pr[hh] += __shfl_xor(pr[hh], 4); pr[hh] += __shfl_xor(pr[hh], 8);
    }
    if (n < NNODES){
      if (c < 4){ elv[n*NHEADS + c] = pl[c]; erv[n*NHEADS + c] = pr[c]; }
      #pragma unroll
      for (int ct = 0; ct < 8; ct++)
        feat[(size_t)n*HD + ct*16 + c] = __float2half_rn(acc[ct][r]);
    }
  }
}

// -------- fused edge-softmax + aggregation, 8 edges in flight + srcs prefetch -----
// Round-13 lesson: TLP beats per-wave ILP (VGPR 28 / 8-edge layout is the sweet
// spot; 32-edge batching killed occupancy). This round: (1) prefetch next
// iteration's srcs index (chain depth 2 -> 1 per iteration, +2 VGPR only);
// (2) f32x8 packed accumulate (__builtin_convertvector + vector-scalar FMA)
// so the compiler emits packed cvt / v_pk_fma_f32 — VALUBusy was 55%.
// No max subtraction (round-9): exp(e)/sum == exp(e-m)/sum(e-m); e <= ~15 << 88.
__global__ __launch_bounds__(256) void smax_agg_kernel(
    const int* __restrict__ rowptr, const int* __restrict__ srcs,
    const float* __restrict__ elv, const float* __restrict__ erv,
    const __half* __restrict__ feat, float* __restrict__ emb_out, int n)
{
  int wid  = (int)((blockIdx.x*(size_t)blockDim.x + threadIdx.x) >> 6);
  int lane = threadIdx.x & 63;
  if (wid >= n) return;
  int s0 = rowptr[wid], s1 = rowptr[wid+1];
  int g   = lane >> 3;                // edge group 0..7
  int fl8 = lane & 7;                 // feature chunk: features fl8*16..+15
  int fo  = fl8 * 16;

  if (s0 == s1){
    if (g == 0){
      float4 z = make_float4(0.f,0.f,0.f,0.f);
      float* op = emb_out + (size_t)wid*384 + fo;
      *(float4*)(op)      = z;
      *(float4*)(op + 4)  = z;
      *(float4*)(op + 8)  = z;
      *(float4*)(op + 12) = z;
    }
    return;
  }

  float4 er4 = *(const float4*)(erv + (size_t)wid*4);
  int head = fl8 >> 1;
  float erh = (head==0)?er4.x:(head==1)?er4.y:(head==2)?er4.z:er4.w;

  f32x8 acc0 = (f32x8)(0.f), acc1 = (f32x8)(0.f);
  float ssum = 0.f;

  // prefetched index for the first iteration
  int  e0 = s0 + g;
  bool vn = (e0 < s1);
  int  sn = vn ? srcs[e0] : 0;

  for (int i = s0; i < s1; i += 8){
    bool v = vn; int s = sn;
    int en = i + 8 + g;                 // prefetch next iteration's index NOW
    vn = (en < s1);
    sn = vn ? srcs[en] : 0;

    float a = v ? __expf(lrelu(elv[(size_t)s*4 + head] + erh)) : 0.f;
    ssum += a;
    const __half* fr = feat + (size_t)s*HD + fo;
    f16x8 h0 = *(const f16x8*)(fr);
    f16x8 h1 = *(const f16x8*)(fr + 8);
    f32x8 f0 = __builtin_convertvector(h0, f32x8);
    f32x8 f1 = __builtin_convertvector(h1, f32x8);
    acc0 += f0 * a;
    acc1 += f1 * a;
  }

  float accv[16];
  #pragma unroll
  for (int j = 0; j < 8; j++){ accv[j] = acc0[j]; accv[8+j] = acc1[j]; }
  #pragma unroll
  for (int j = 0; j < 16; j++){
    accv[j] += __shfl_xor(accv[j], 8);
    accv[j] += __shfl_xor(accv[j], 16);
    accv[j] += __shfl_xor(accv[j], 32);
  }
  ssum += __shfl_xor(ssum, 8);
  ssum += __shfl_xor(ssum, 16);
  ssum += __shfl_xor(ssum, 32);

  if (g == 0){
    float inv = 1.f / ssum;
    float* op = emb_out + (size_t)wid*384 + fo;
    float4 o;
    o.x = elu(accv[0]*inv);  o.y = elu(accv[1]*inv);
    o.z = elu(accv[2]*inv);  o.w = elu(accv[3]*inv);
    *(float4*)(op) = o;
    o.x = elu(accv[4]*inv);  o.y = elu(accv[5]*inv);
    o.z = elu(accv[6]*inv);  o.w = elu(accv[7]*inv);
    *(float4*)(op + 4) = o;
    o.x = elu(accv[8]*inv);  o.y = elu(accv[9]*inv);
    o.z = elu(accv[10]*inv); o.w = elu(accv[11]*inv);
    *(float4*)(op + 8) = o;
    o.x = elu(accv[12]*inv); o.y = elu(accv[13]*inv);
    o.z = elu(accv[14]*inv); o.w = elu(accv[15]*inv);
    *(float4*)(op + 12) = o;
  }
}

// ---------------- final projection: emb[N,384] @ Wproj[384,32], split-K partials --------
__global__ __launch_bounds__(256) void proj_kernel(
    const float* __restrict__ emb, const float* __restrict__ Wp, float* __restrict__ part)
{
  __shared__ float As[PTILE*36];
  __shared__ float Wl[32*32];
  int t = threadIdx.x;
  int tx = t & 3, ty = t >> 2;
  int rbase = blockIdx.x * PTILE;
  int kstart = blockIdx.y * 192;
  float* pout = part + (size_t)blockIdx.y * NNODES * 32;

  float acc[2][8];
  #pragma unroll
  for (int r = 0; r < 2; r++)
    #pragma unroll
    for (int j = 0; j < 8; j++) acc[r][j] = 0.f;

  for (int kb = kstart; kb < kstart + 192; kb += 32){
    #pragma unroll
    for (int i = 0; i < 4; i++){
      int idx = i*256 + t;
      int row = idx >> 3;
      int kq  = (idx & 7) * 4;
      int gr  = rbase + row;
      float4 v = make_float4(0.f,0.f,0.f,0.f);
      if (gr < NNODES) v = *(const float4*)(emb + (size_t)gr*384 + kb + kq);
      *(float4*)&As[row*36 + kq] = v;
    }
    *(float4*)&Wl[t*4] = *(const float4*)(Wp + (size_t)kb*32 + t*4);
    __syncthreads();

    #pragma unroll 8
    for (int k = 0; k < 32; k++){
      float4 b0 = *(const float4*)&Wl[k*32 + tx*8];
      float4 b1 = *(const float4*)&Wl[k*32 + tx*8 + 4];
      #pragma unroll
      for (int r = 0; r < 2; r++){
        float a = As[(ty + 64*r)*36 + k];
        acc[r][0] += a*b0.x; acc[r][1] += a*b0.y;
        acc[r][2] += a*b0.z; acc[r][3] += a*b0.w;
        acc[r][4] += a*b1.x; acc[r][5] += a*b1.y;
        acc[r][6] += a*b1.z; acc[r][7] += a*b1.w;
      }
    }
    __syncthreads();
  }

  #pragma unroll
  for (int r = 0; r < 2; r++){
    int n = rbase + ty + 64*r;
    if (n < NNODES){
      *(float4*)(pout + (size_t)n*32 + tx*8)     = make_float4(acc[r][0], acc[r][1], acc[r][2], acc[r][3]);
      *(float4*)(pout + (size_t)n*32 + tx*8 + 4) = make_float4(acc[r][4], acc[r][5], acc[r][6], acc[r][7]);
    }
  }
}

__global__ void proj_reduce_kernel(const float4* __restrict__ part, float4* __restrict__ out, int n4){
  int i = blockIdx.x*blockDim.x + threadIdx.x;
  if (i >= n4) return;
  float4 a = part[i];
  float4 b = part[n4 + i];
  out[i] = make_float4(a.x + b.x, a.y + b.y, a.z + b.z, a.w + b.w);
}

// ---------------- launch ----------------
extern "C" void kernel_launch(void* const* d_in, const int* in_sizes, int n_in,
                              void* d_out, int out_size, void* d_ws, size_t ws_size,
                              hipStream_t stream) {
  const float* x    = (const float*)d_in[0];
  const int*   src  = (const int*)d_in[1];
  const int*   dst  = (const int*)d_in[2];
  const float* Ws_[3]  = { (const float*)d_in[3], (const float*)d_in[6], (const float*)d_in[9]  };
  const float* als[3] = { (const float*)d_in[4], (const float*)d_in[7], (const float*)d_in[10] };
  const float* ars[3] = { (const float*)d_in[5], (const float*)d_in[8], (const float*)d_in[11] };
  const float* Wproj  = (const float*)d_in[12];
  float* out = (float*)d_out;

  char* wptr = (char*)d_ws;
  auto alloc = [&](size_t bytes) -> void* {
    void* p = (void*)wptr; wptr += (bytes + 255) & ~(size_t)255; return p;
  };
  int*      btail      = (int*)     alloc((size_t)NBUCK*4);
  int*      ebase      = (int*)     alloc((size_t)NBUCK*4);
  unsigned* bstage     = (unsigned*)alloc((size_t)NBUCK*BCAP*4);
  int*      rowptr     = (int*)     alloc((size_t)(NNODES+1)*4);
  int*      src_sorted = (int*)     alloc((size_t)NEDGES*4);
  __half*   feat       = (__half*)  alloc((size_t)NNODES*HD*2);
  float*    elv        = (float*)   alloc((size_t)NNODES*NHEADS*4);
  float*    erv        = (float*)   alloc((size_t)NNODES*NHEADS*4);
  float*    emb        = (float*)   alloc((size_t)NNODES*384*4);
  float*    part       = (float*)   alloc((size_t)2*NNODES*32*4);
  _Float16* wt         = (_Float16*)alloc((size_t)3*HD*HD*2);

  // CSR build, bucketed (LDS-local scatter)
  init_btail_kernel<<<1, 256, 0, stream>>>(btail);
  p1_bucket_kernel<<<(NEDGES + P1_EPB - 1)/P1_EPB, P1_T, 0, stream>>>(
      src, dst, btail, bstage, NEDGES);
  bucket_scan_kernel<<<1, 64, 0, stream>>>(btail, ebase, rowptr);
  p2_csr_kernel<<<NBUCK, P2_T, 0, stream>>>(bstage, btail, ebase, rowptr, src_sorted);

  // W transpose+fp16 prep (all 3 layers)
  wprep_kernel<<<(3*HD*HD + 255)/256, 256, 0, stream>>>(Ws_[0], Ws_[1], Ws_[2], wt);

  const float* hin = x;
  int hstride = 128;
  for (int l = 0; l < 3; l++){
    gemm_feat_kernel<<<(NNODES + TILE_R - 1)/TILE_R, 256, 0, stream>>>(
        hin, hstride, wt + (size_t)l*HD*HD, als[l], ars[l], feat, elv, erv);
    smax_agg_kernel<<<(NNODES*64+255)/256, 256, 0, stream>>>(rowptr, src_sorted, elv, erv,
                                                             feat, emb + (size_t)l*128, NNODES);
    hin = emb + (size_t)l*128;
    hstride = 384;
  }

  dim3 pgrid((NNODES + PTILE - 1)/PTILE, 2);
  proj_kernel<<<pgrid, 256, 0, stream>>>(emb, Wproj, part);
  const int OUT4 = NNODES*32/4;
  proj_reduce_kernel<<<(OUT4+255)/256, 256, 0, stream>>>((const float4*)part, (float4*)out, OUT4);
}

// Round 16
// 317.852 us; speedup vs baseline: 1.1362x; 1.0026x over previous
//
#include <hip/hip_runtime.h>
#include <hip/hip_fp16.h>
#include <math.h>

#define NNODES 50000
#define NEDGES 800000
#define HD     128      // H*D
#define NHEADS 4
#define DH     32

#define TILE_R 64       // gemm rows per block
#define AKPF   136      // full-K padded stride (halves)

#define PTILE  128      // proj rows per block; split-K=2 partial buffers + reduce
                        // (round-6 lesson: NEVER split-K via global atomicAdd)

// Bucketed CSR build (round-9 lesson: naive 4B random scatter = 17x write amp;
// all fine-grained scatter must happen in LDS).
#define NBUCK  196
#define BCAP   6144
#define P1_T   512
#define P1_EPB 4096
#define P2_T   512

struct alignas(16) Half8 { __half2 a, b, c, d; };
typedef _Float16 f16x8 __attribute__((ext_vector_type(8)));
typedef float    f32x4 __attribute__((ext_vector_type(4)));
typedef float    f32x8 __attribute__((ext_vector_type(8)));

static __device__ __forceinline__ float lrelu(float x){ return x > 0.f ? x : 0.2f*x; }
static __device__ __forceinline__ float elu(float x){ return x > 0.f ? x : __expf(x) - 1.f; }

// ---------------- CSR build, bucketed ----------------

__global__ void init_btail_kernel(int* btail){
  int b = blockIdx.x*blockDim.x + threadIdx.x;
  if (b < NBUCK) btail[b] = b*BCAP;
}

__global__ __launch_bounds__(P1_T) void p1_bucket_kernel(
    const int* __restrict__ src, const int* __restrict__ dst,
    int* __restrict__ btail, unsigned int* __restrict__ bstage, int e)
{
  __shared__ int cnt[NBUCK];
  __shared__ int gstart[NBUCK];
  int t = threadIdx.x;
  int base = blockIdx.x * P1_EPB;
  for (int i = t; i < NBUCK; i += P1_T) cnt[i] = 0;
  __syncthreads();
  int s_[8], b_[8], dl_[8];
  #pragma unroll
  for (int j = 0; j < 8; j++){
    int i = base + j*P1_T + t;
    if (i < e){
      int d = dst[i];
      s_[j]  = src[i];
      b_[j]  = d >> 8;
      dl_[j] = d & 255;
      atomicAdd(&cnt[b_[j]], 1);
    } else b_[j] = -1;
  }
  __syncthreads();
  for (int i = t; i < NBUCK; i += P1_T){
    gstart[i] = cnt[i] ? atomicAdd(&btail[i], cnt[i]) : 0;
    cnt[i] = 0;
  }
  __syncthreads();
  #pragma unroll
  for (int j = 0; j < 8; j++){
    if (b_[j] >= 0){
      int p = atomicAdd(&cnt[b_[j]], 1);
      bstage[(size_t)gstart[b_[j]] + p] = ((unsigned)dl_[j] << 16) | (unsigned)s_[j];
    }
  }
}

__global__ void bucket_scan_kernel(const int* __restrict__ btail, int* __restrict__ ebase,
                                   int* __restrict__ rowptr){
  if (blockIdx.x == 0 && threadIdx.x == 0){
    int run = 0;
    for (int b = 0; b < NBUCK; b++){
      ebase[b] = run;
      run += btail[b] - b*BCAP;
    }
    rowptr[NNODES] = run;
  }
}

__global__ __launch_bounds__(P2_T) void p2_csr_kernel(
    const unsigned int* __restrict__ bstage, const int* __restrict__ btail,
    const int* __restrict__ ebase, int* __restrict__ rowptr, int* __restrict__ srcs)
{
  __shared__ unsigned int ebuf[BCAP];
  __shared__ unsigned short sorted[BCAP];
  __shared__ int cnt[256], ofs[256], run[256];
  int b = blockIdx.x, t = threadIdx.x;
  int nE = btail[b] - b*BCAP;
  int gb = ebase[b];
  const unsigned int* bp = bstage + (size_t)b*BCAP;

  for (int i = t; i < 256; i += P2_T) cnt[i] = 0;
  __syncthreads();
  for (int i = t; i < nE; i += P2_T){
    unsigned int v = bp[i];
    ebuf[i] = v;
    atomicAdd(&cnt[v >> 16], 1);
  }
  __syncthreads();
  if (t < 256) ofs[t] = cnt[t];
  __syncthreads();
  for (int off = 1; off < 256; off <<= 1){
    int v = 0;
    if (t < 256 && t >= off) v = ofs[t - off];
    __syncthreads();
    if (t < 256) ofs[t] += v;
    __syncthreads();
  }
  if (t < 256){
    int ex = ofs[t] - cnt[t];
    run[t] = ex;
    int node = b*256 + t;
    if (node < NNODES) rowptr[node] = gb + ex;
  }
  __syncthreads();
  for (int i = t; i < nE; i += P2_T){
    unsigned int v = ebuf[i];
    int p = atomicAdd(&run[v >> 16], 1);
    sorted[p] = (unsigned short)(v & 0xFFFFu);
  }
  __syncthreads();
  for (int i = t; i < nE; i += P2_T)
    srcs[gb + i] = (int)sorted[i];
}

// ---------------- W prep: transpose+convert W[l][k][n] -> Wt[l][n][k] fp16 ----------------
__global__ void wprep_kernel(const float* __restrict__ W0, const float* __restrict__ W1,
                             const float* __restrict__ W2, _Float16* __restrict__ wt){
  int id = blockIdx.x*blockDim.x + threadIdx.x;     // 3*16384
  if (id >= 3*16384) return;
  int l = id >> 14, rem = id & 16383;
  int n = rem >> 7, k = rem & 127;
  const float* W = (l==0) ? W0 : (l==1) ? W1 : W2;
  wt[(size_t)l*16384 + n*128 + k] = (_Float16)W[k*128 + n];
}

// ---------------- GEMM (h @ W) via MFMA fp16, full-K single-barrier staging ----------------
// Templated input: layer 0 reads fp32 x (stride 128); layers 1-2 read fp16 emb
// (stride 384) directly — halves A-read traffic and drops the cvt (round-16).
template<bool FP16IN>
__global__ __launch_bounds__(256) void gemm_feat_kernel(
    const void* __restrict__ hin, int hstride,
    const _Float16* __restrict__ Wt,   // [128 n][128 k] fp16 (pre-transposed)
    const float* __restrict__ al, const float* __restrict__ ar,
    __half* __restrict__ feat, float* __restrict__ elv, float* __restrict__ erv)
{
  __shared__ __align__(16) _Float16 Ah[TILE_R*AKPF];  // 17408 B
  __shared__ __align__(16) _Float16 Wh[HD*AKPF];      // 34816 B
  int t = threadIdx.x;
  int w = t >> 6, lane = t & 63;
  int c = lane & 15, quad = lane >> 4;
  int rbase = blockIdx.x * TILE_R;

  f32x4 acc[8];
  #pragma unroll
  for (int ct = 0; ct < 8; ct++) acc[ct] = (f32x4){0.f, 0.f, 0.f, 0.f};

  int arow = t >> 2;
  int akq  = t & 3;
  int an   = rbase + arow;
  if (FP16IN){
    const _Float16* ap = (const _Float16*)hin + (size_t)an*hstride + akq*8;
    #pragma unroll
    for (int kb = 0; kb < HD; kb += 32){
      f16x8 av = (f16x8)((_Float16)0);
      if (an < NNODES) av = *(const f16x8*)(ap + kb);
      *(f16x8*)&Ah[arow*AKPF + kb + akq*8] = av;
    }
  } else {
    const float* ap = (const float*)hin + (size_t)an*hstride + akq*8;
    #pragma unroll
    for (int kb = 0; kb < HD; kb += 32){
      float4 v0 = make_float4(0.f,0.f,0.f,0.f), v1 = v0;
      if (an < NNODES){
        v0 = *(const float4*)(ap + kb);
        v1 = *(const float4*)(ap + kb + 4);
      }
      f16x8 av;
      av[0]=(_Float16)v0.x; av[1]=(_Float16)v0.y; av[2]=(_Float16)v0.z; av[3]=(_Float16)v0.w;
      av[4]=(_Float16)v1.x; av[5]=(_Float16)v1.y; av[6]=(_Float16)v1.z; av[7]=(_Float16)v1.w;
      *(f16x8*)&Ah[arow*AKPF + kb + akq*8] = av;
    }
  }
  int wn = t >> 1;
  int wk = (t & 1) * 16;
  const _Float16* wp = Wt + wn*HD + wk;
  #pragma unroll
  for (int kb = 0; kb < HD; kb += 32){
    *(uint4*)&Wh[wn*AKPF + kb + wk]     = *(const uint4*)(wp + kb);
    *(uint4*)&Wh[wn*AKPF + kb + wk + 8] = *(const uint4*)(wp + kb + 8);
  }
  __syncthreads();

  #pragma unroll
  for (int kb = 0; kb < HD; kb += 32){
    f16x8 afrag = *(const f16x8*)&Ah[(w*16 + c)*AKPF + kb + quad*8];
    #pragma unroll
    for (int ct = 0; ct < 8; ct++){
      f16x8 bfrag = *(const f16x8*)&Wh[(ct*16 + c)*AKPF + kb + quad*8];
      acc[ct] = __builtin_amdgcn_mfma_f32_16x16x32_f16(afrag, bfrag, acc[ct], 0, 0, 0);
    }
  }

  float alv[8], arv[8];
  #pragma unroll
  for (int ct = 0; ct < 8; ct++){
    int idx = (ct >> 1)*DH + (ct & 1)*16 + c;
    alv[ct] = al[idx];
    arv[ct] = ar[idx];
  }
  #pragma unroll
  for (int r = 0; r < 4; r++){
    int n = rbase + w*16 + quad*4 + r;
    float pl[4], pr[4];
    #pragma unroll
    for (int hh = 0; hh < 4; hh++){
      pl[hh] = acc[2*hh][r]*alv[2*hh] + acc[2*hh+1][r]*alv[2*hh+1];
      pr[hh] = acc[2*hh][r]*arv[2*hh] + acc[2*hh+1][r]*arv[2*hh+1];
    }
    #pragma unroll
    for (int hh = 0; hh < 4; hh++){
      pl[hh] += __shfl_xor(pl[hh], 1); pl[hh] += __shfl_xor(pl[hh], 2);
      pl[hh] += __shfl_xor(pl[hh], 4); pl[hh] += __shfl_xor(pl[hh], 8);
      pr[hh] += __shfl_xor(pr[hh], 1); pr[hh] += __shfl_xor(pr[hh], 2);
      pr[hh] += __shfl_xor(pr[hh], 4); pr[hh] += __shfl_xor(pr[hh], 8);
    }
    if (n < NNODES){
      if (c < 4){ elv[n*NHEADS + c] = pl[c]; erv[n*NHEADS + c] = pr[c]; }
      #pragma unroll
      for (int ct = 0; ct < 8; ct++)
        feat[(size_t)n*HD + ct*16 + c] = __float2half_rn(acc[ct][r]);
    }
  }
}

// -------- fused edge-softmax + aggregation, 8 edges in flight + srcs prefetch -----
// emb_out fp16 (round-16): halves the 25 MB write. Round-13 lesson: TLP beats
// per-wave ILP (VGPR ~24 / 8-edge layout). No max subtraction (round-9).
__global__ __launch_bounds__(256) void smax_agg_kernel(
    const int* __restrict__ rowptr, const int* __restrict__ srcs,
    const float* __restrict__ elv, const float* __restrict__ erv,
    const __half* __restrict__ feat, __half* __restrict__ emb_out, int n)
{
  int wid  = (int)((blockIdx.x*(size_t)blockDim.x + threadIdx.x) >> 6);
  int lane = threadIdx.x & 63;
  if (wid >= n) return;
  int s0 = rowptr[wid], s1 = rowptr[wid+1];
  int g   = lane >> 3;
  int fl8 = lane & 7;
  int fo  = fl8 * 16;

  if (s0 == s1){
    if (g == 0){
      uint4 z = make_uint4(0,0,0,0);
      __half* op = emb_out + (size_t)wid*384 + fo;
      *(uint4*)(op)     = z;
      *(uint4*)(op + 8) = z;
    }
    return;
  }

  float4 er4 = *(const float4*)(erv + (size_t)wid*4);
  int head = fl8 >> 1;
  float erh = (head==0)?er4.x:(head==1)?er4.y:(head==2)?er4.z:er4.w;

  f32x8 acc0 = (f32x8)(0.f), acc1 = (f32x8)(0.f);
  float ssum = 0.f;

  int  e0 = s0 + g;
  bool vn = (e0 < s1);
  int  sn = vn ? srcs[e0] : 0;

  for (int i = s0; i < s1; i += 8){
    bool v = vn; int s = sn;
    int en = i + 8 + g;
    vn = (en < s1);
    sn = vn ? srcs[en] : 0;

    float a = v ? __expf(lrelu(elv[(size_t)s*4 + head] + erh)) : 0.f;
    ssum += a;
    const __half* fr = feat + (size_t)s*HD + fo;
    f16x8 h0 = *(const f16x8*)(fr);
    f16x8 h1 = *(const f16x8*)(fr + 8);
    f32x8 f0 = __builtin_convertvector(h0, f32x8);
    f32x8 f1 = __builtin_convertvector(h1, f32x8);
    acc0 += f0 * a;
    acc1 += f1 * a;
  }

  float accv[16];
  #pragma unroll
  for (int j = 0; j < 8; j++){ accv[j] = acc0[j]; accv[8+j] = acc1[j]; }
  #pragma unroll
  for (int j = 0; j < 16; j++){
    accv[j] += __shfl_xor(accv[j], 8);
    accv[j] += __shfl_xor(accv[j], 16);
    accv[j] += __shfl_xor(accv[j], 32);
  }
  ssum += __shfl_xor(ssum, 8);
  ssum += __shfl_xor(ssum, 16);
  ssum += __shfl_xor(ssum, 32);

  if (g == 0){
    float inv = 1.f / ssum;
    __half2 h[8];
    #pragma unroll
    for (int j = 0; j < 8; j++)
      h[j] = __floats2half2_rn(elu(accv[2*j]*inv), elu(accv[2*j+1]*inv));
    __half* op = emb_out + (size_t)wid*384 + fo;
    *(uint4*)(op)     = *(uint4*)&h[0];
    *(uint4*)(op + 8) = *(uint4*)&h[4];
  }
}

// ---------------- final projection: emb[N,384] fp16 @ Wproj[384,32], split-K partials ----
__global__ __launch_bounds__(256) void proj_kernel(
    const __half* __restrict__ emb, const float* __restrict__ Wp, float* __restrict__ part)
{
  __shared__ float As[PTILE*36];
  __shared__ float Wl[32*32];
  int t = threadIdx.x;
  int tx = t & 3, ty = t >> 2;
  int rbase = blockIdx.x * PTILE;
  int kstart = blockIdx.y * 192;
  float* pout = part + (size_t)blockIdx.y * NNODES * 32;

  float acc[2][8];
  #pragma unroll
  for (int r = 0; r < 2; r++)
    #pragma unroll
    for (int j = 0; j < 8; j++) acc[r][j] = 0.f;

  for (int kb = kstart; kb < kstart + 192; kb += 32){
    // stage A: 128 rows x 32 k = 4096 halves = 512 h8-chunks, 2 per thread
    #pragma unroll
    for (int i = 0; i < 2; i++){
      int idx = i*256 + t;          // 0..511
      int row = idx >> 2;           // 0..127
      int kq  = (idx & 3) * 8;      // 0,8,16,24
      int gr  = rbase + row;
      f16x8 v = (f16x8)((_Float16)0);
      if (gr < NNODES) v = *(const f16x8*)((const _Float16*)emb + (size_t)gr*384 + kb + kq);
      float4 f0, f1;
      f0.x=(float)v[0]; f0.y=(float)v[1]; f0.z=(float)v[2]; f0.w=(float)v[3];
      f1.x=(float)v[4]; f1.y=(float)v[5]; f1.z=(float)v[6]; f1.w=(float)v[7];
      *(float4*)&As[row*36 + kq]     = f0;
      *(float4*)&As[row*36 + kq + 4] = f1;
    }
    *(float4*)&Wl[t*4] = *(const float4*)(Wp + (size_t)kb*32 + t*4);
    __syncthreads();

    #pragma unroll 8
    for (int k = 0; k < 32; k++){
      float4 b0 = *(const float4*)&Wl[k*32 + tx*8];
      float4 b1 = *(const float4*)&Wl[k*32 + tx*8 + 4];
      #pragma unroll
      for (int r = 0; r < 2; r++){
        float a = As[(ty + 64*r)*36 + k];
        acc[r][0] += a*b0.x; acc[r][1] += a*b0.y;
        acc[r][2] += a*b0.z; acc[r][3] += a*b0.w;
        acc[r][4] += a*b1.x; acc[r][5] += a*b1.y;
        acc[r][6] += a*b1.z; acc[r][7] += a*b1.w;
      }
    }
    __syncthreads();
  }

  #pragma unroll
  for (int r = 0; r < 2; r++){
    int n = rbase + ty + 64*r;
    if (n < NNODES){
      *(float4*)(pout + (size_t)n*32 + tx*8)     = make_float4(acc[r][0], acc[r][1], acc[r][2], acc[r][3]);
      *(float4*)(pout + (size_t)n*32 + tx*8 + 4) = make_float4(acc[r][4], acc[r][5], acc[r][6], acc[r][7]);
    }
  }
}

__global__ void proj_reduce_kernel(const float4* __restrict__ part, float4* __restrict__ out, int n4){
  int i = blockIdx.x*blockDim.x + threadIdx.x;
  if (i >= n4) return;
  float4 a = part[i];
  float4 b = part[n4 + i];
  out[i] = make_float4(a.x + b.x, a.y + b.y, a.z + b.z, a.w + b.w);
}

// ---------------- launch ----------------
extern "C" void kernel_launch(void* const* d_in, const int* in_sizes, int n_in,
                              void* d_out, int out_size, void* d_ws, size_t ws_size,
                              hipStream_t stream) {
  const float* x    = (const float*)d_in[0];
  const int*   src  = (const int*)d_in[1];
  const int*   dst  = (const int*)d_in[2];
  const float* Ws_[3]  = { (const float*)d_in[3], (const float*)d_in[6], (const float*)d_in[9]  };
  const float* als[3] = { (const float*)d_in[4], (const float*)d_in[7], (const float*)d_in[10] };
  const float* ars[3] = { (const float*)d_in[5], (const float*)d_in[8], (const float*)d_in[11] };
  const float* Wproj  = (const float*)d_in[12];
  float* out = (float*)d_out;

  char* wptr = (char*)d_ws;
  auto alloc = [&](size_t bytes) -> void* {
    void* p = (void*)wptr; wptr += (bytes + 255) & ~(size_t)255; return p;
  };
  int*      btail      = (int*)     alloc((size_t)NBUCK*4);
  int*      ebase      = (int*)     alloc((size_t)NBUCK*4);
  unsigned* bstage     = (unsigned*)alloc((size_t)NBUCK*BCAP*4);
  int*      rowptr     = (int*)     alloc((size_t)(NNODES+1)*4);
  int*      src_sorted = (int*)     alloc((size_t)NEDGES*4);
  __half*   feat       = (__half*)  alloc((size_t)NNODES*HD*2);
  float*    elv        = (float*)   alloc((size_t)NNODES*NHEADS*4);
  float*    erv        = (float*)   alloc((size_t)NNODES*NHEADS*4);
  __half*   emb        = (__half*)  alloc((size_t)NNODES*384*2);
  float*    part       = (float*)   alloc((size_t)2*NNODES*32*4);
  _Float16* wt         = (_Float16*)alloc((size_t)3*HD*HD*2);

  // CSR build, bucketed (LDS-local scatter)
  init_btail_kernel<<<1, 256, 0, stream>>>(btail);
  p1_bucket_kernel<<<(NEDGES + P1_EPB - 1)/P1_EPB, P1_T, 0, stream>>>(
      src, dst, btail, bstage, NEDGES);
  bucket_scan_kernel<<<1, 64, 0, stream>>>(btail, ebase, rowptr);
  p2_csr_kernel<<<NBUCK, P2_T, 0, stream>>>(bstage, btail, ebase, rowptr, src_sorted);

  // W transpose+fp16 prep (all 3 layers)
  wprep_kernel<<<(3*HD*HD + 255)/256, 256, 0, stream>>>(Ws_[0], Ws_[1], Ws_[2], wt);

  const int NGB = (NNODES + TILE_R - 1)/TILE_R;
  // layer 0: fp32 x input
  gemm_feat_kernel<false><<<NGB, 256, 0, stream>>>(
      (const void*)x, 128, wt, als[0], ars[0], feat, elv, erv);
  smax_agg_kernel<<<(NNODES*64+255)/256, 256, 0, stream>>>(rowptr, src_sorted, elv, erv,
                                                           feat, emb, NNODES);
  // layers 1,2: fp16 emb input (previous layer's 128-wide slice)
  for (int l = 1; l < 3; l++){
    gemm_feat_kernel<true><<<NGB, 256, 0, stream>>>(
        (const void*)(emb + (size_t)(l-1)*128), 384,
        wt + (size_t)l*HD*HD, als[l], ars[l], feat, elv, erv);
    smax_agg_kernel<<<(NNODES*64+255)/256, 256, 0, stream>>>(rowptr, src_sorted, elv, erv,
                                                             feat, emb + (size_t)l*128, NNODES);
  }

  dim3 pgrid((NNODES + PTILE - 1)/PTILE, 2);
  proj_kernel<<<pgrid, 256, 0, stream>>>(emb, Wproj, part);
  const int OUT4 = NNODES*32/4;
  proj_reduce_kernel<<<(OUT4+255)/256, 256, 0, stream>>>((const float4*)part, (float4*)out, OUT4);
}